// Round 7
// baseline (1277.511 us; speedup 1.0000x reference)
//
#include <hip/hip_runtime.h>

// Wav2Vec BLSTM: 4-layer bi-LSTM (B=32, T=1000, H=32, G=128) + mean-pool + fc.
//
// Round 7: matvec+broadcast as hand-pipelined inline asm.
//  - v_readlane_b32 writes h values directly into hard-coded SGPRs s64..s95
//    (clobbered); v_pk_fma_f32 consumes s[2k:2k+1] pairs directly -> zero
//    SALU packing.
//  - 5 volatile asm blocks software-pipeline readlanes of group g+1 against
//    pk_fmas of group g (sgpr write->read distance >= 16 cy).
//  - tail trimmed: si*tg == v0*o0 in both halves (select-free); only sf/so
//    need a cndmask each.
// Kept (verified): -log2e / -2log2e prescale in weights + GEMM epilogue,
// permlane32_swap exchange, transposed/time-reversed xpT streams, clamped
// unconditional prefetch, branch-free h store.

#define TB 1000
#define LOG2E 1.44269504088896340736f

typedef int   v2i __attribute__((ext_vector_type(2)));
typedef float v2f __attribute__((ext_vector_type(2)));

__device__ __forceinline__ float fexp2(float x) {
#if __has_builtin(__builtin_amdgcn_exp2f)
    return __builtin_amdgcn_exp2f(x);
#else
    return exp2f(x);
#endif
}

// returns v[lane ^ 32]; pickx precomputed per-lane (convention-independent)
__device__ __forceinline__ float lane_xor32(float v, bool pickx) {
    v2i r = __builtin_amdgcn_permlane32_swap(__float_as_int(v), __float_as_int(v),
                                             false, false);
    return __int_as_float(pickx ? r[0] : r[1]);
}

// gates = {GA,GB} + h . {Wa,Wb}^T ; h broadcast via readlane into s64..s95,
// pk_fma on sgpr pairs. wa/wb: 16 v2f each (prescaled). Returns g0,g1.
__device__ __forceinline__ void matvec_rl(int hbits, const v2f* wa, const v2f* wb,
                                          float GA, float GB, float& g0, float& g1)
{
    v2f qa0 = {GA, 0.0f}, qa1 = {0.0f, 0.0f}, qa2 = {0.0f, 0.0f}, qa3 = {0.0f, 0.0f};
    v2f qb0 = {GB, 0.0f}, qb1 = {0.0f, 0.0f}, qb2 = {0.0f, 0.0f}, qb3 = {0.0f, 0.0f};

    // B0: h[0..7] -> s64..71
    asm volatile(
        "v_readlane_b32 s64, %0, 0\n\t"
        "v_readlane_b32 s65, %0, 1\n\t"
        "v_readlane_b32 s66, %0, 2\n\t"
        "v_readlane_b32 s67, %0, 3\n\t"
        "v_readlane_b32 s68, %0, 4\n\t"
        "v_readlane_b32 s69, %0, 5\n\t"
        "v_readlane_b32 s70, %0, 6\n\t"
        "v_readlane_b32 s71, %0, 7"
        :: "v"(hbits)
        : "s64","s65","s66","s67","s68","s69","s70","s71");

    // B1: rl h[8..15] -> s72..79 ; pk group0 (pairs s64:65..s70:71)
    asm volatile(
        "v_readlane_b32 s72, %4, 8\n\t"
        "v_pk_fma_f32 %0, s[64:65], %5, %0\n\t"
        "v_readlane_b32 s73, %4, 9\n\t"
        "v_pk_fma_f32 %1, s[64:65], %6, %1\n\t"
        "v_readlane_b32 s74, %4, 10\n\t"
        "v_pk_fma_f32 %2, s[68:69], %7, %2\n\t"
        "v_readlane_b32 s75, %4, 11\n\t"
        "v_pk_fma_f32 %3, s[68:69], %8, %3\n\t"
        "v_readlane_b32 s76, %4, 12\n\t"
        "v_pk_fma_f32 %0, s[66:67], %9, %0\n\t"
        "v_readlane_b32 s77, %4, 13\n\t"
        "v_pk_fma_f32 %1, s[66:67], %10, %1\n\t"
        "v_readlane_b32 s78, %4, 14\n\t"
        "v_pk_fma_f32 %2, s[70:71], %11, %2\n\t"
        "v_readlane_b32 s79, %4, 15\n\t"
        "v_pk_fma_f32 %3, s[70:71], %12, %3"
        : "+v"(qa0), "+v"(qb0), "+v"(qa1), "+v"(qb1)
        : "v"(hbits), "v"(wa[0]), "v"(wb[0]), "v"(wa[2]), "v"(wb[2]),
          "v"(wa[1]), "v"(wb[1]), "v"(wa[3]), "v"(wb[3])
        : "s72","s73","s74","s75","s76","s77","s78","s79");

    // B2: rl h[16..23] -> s80..87 ; pk group1 (pairs s72:73..s78:79)
    asm volatile(
        "v_readlane_b32 s80, %4, 16\n\t"
        "v_pk_fma_f32 %0, s[72:73], %5, %0\n\t"
        "v_readlane_b32 s81, %4, 17\n\t"
        "v_pk_fma_f32 %1, s[72:73], %6, %1\n\t"
        "v_readlane_b32 s82, %4, 18\n\t"
        "v_pk_fma_f32 %2, s[76:77], %7, %2\n\t"
        "v_readlane_b32 s83, %4, 19\n\t"
        "v_pk_fma_f32 %3, s[76:77], %8, %3\n\t"
        "v_readlane_b32 s84, %4, 20\n\t"
        "v_pk_fma_f32 %0, s[74:75], %9, %0\n\t"
        "v_readlane_b32 s85, %4, 21\n\t"
        "v_pk_fma_f32 %1, s[74:75], %10, %1\n\t"
        "v_readlane_b32 s86, %4, 22\n\t"
        "v_pk_fma_f32 %2, s[78:79], %11, %2\n\t"
        "v_readlane_b32 s87, %4, 23\n\t"
        "v_pk_fma_f32 %3, s[78:79], %12, %3"
        : "+v"(qa2), "+v"(qb2), "+v"(qa3), "+v"(qb3)
        : "v"(hbits), "v"(wa[4]), "v"(wb[4]), "v"(wa[6]), "v"(wb[6]),
          "v"(wa[5]), "v"(wb[5]), "v"(wa[7]), "v"(wb[7])
        : "s80","s81","s82","s83","s84","s85","s86","s87");

    // B3: rl h[24..31] -> s88..95 ; pk group2 (pairs s80:81..s86:87)
    asm volatile(
        "v_readlane_b32 s88, %4, 24\n\t"
        "v_pk_fma_f32 %0, s[80:81], %5, %0\n\t"
        "v_readlane_b32 s89, %4, 25\n\t"
        "v_pk_fma_f32 %1, s[80:81], %6, %1\n\t"
        "v_readlane_b32 s90, %4, 26\n\t"
        "v_pk_fma_f32 %2, s[84:85], %7, %2\n\t"
        "v_readlane_b32 s91, %4, 27\n\t"
        "v_pk_fma_f32 %3, s[84:85], %8, %3\n\t"
        "v_readlane_b32 s92, %4, 28\n\t"
        "v_pk_fma_f32 %0, s[82:83], %9, %0\n\t"
        "v_readlane_b32 s93, %4, 29\n\t"
        "v_pk_fma_f32 %1, s[82:83], %10, %1\n\t"
        "v_readlane_b32 s94, %4, 30\n\t"
        "v_pk_fma_f32 %2, s[86:87], %11, %2\n\t"
        "v_readlane_b32 s95, %4, 31\n\t"
        "v_pk_fma_f32 %3, s[86:87], %12, %3"
        : "+v"(qa0), "+v"(qb0), "+v"(qa1), "+v"(qb1)
        : "v"(hbits), "v"(wa[8]), "v"(wb[8]), "v"(wa[10]), "v"(wb[10]),
          "v"(wa[9]), "v"(wb[9]), "v"(wa[11]), "v"(wb[11])
        : "s88","s89","s90","s91","s92","s93","s94","s95");

    // B4: pk group3 (pairs s88:89..s94:95)
    asm volatile(
        "v_pk_fma_f32 %0, s[88:89], %4, %0\n\t"
        "v_pk_fma_f32 %1, s[88:89], %5, %1\n\t"
        "v_pk_fma_f32 %2, s[92:93], %6, %2\n\t"
        "v_pk_fma_f32 %3, s[92:93], %7, %3\n\t"
        "v_pk_fma_f32 %0, s[90:91], %8, %0\n\t"
        "v_pk_fma_f32 %1, s[90:91], %9, %1\n\t"
        "v_pk_fma_f32 %2, s[94:95], %10, %2\n\t"
        "v_pk_fma_f32 %3, s[94:95], %11, %3"
        : "+v"(qa2), "+v"(qb2), "+v"(qa3), "+v"(qb3)
        : "v"(wa[12]), "v"(wb[12]), "v"(wa[14]), "v"(wb[14]),
          "v"(wa[13]), "v"(wb[13]), "v"(wa[15]), "v"(wb[15]));

    v2f sa = (qa0 + qa2) + (qa1 + qa3);
    v2f sb = (qb0 + qb2) + (qb1 + qb3);
    g0 = sa[0] + sa[1];
    g1 = sb[0] + sb[1];
}

// ---------------------------------------------------------------------------
// GEMM: A[32000][K] x W[256][K]^T + (bi+bh), then row-dependent prescale by
// -log2e (g-rows: -2log2e) -> xpT[2*32][128][1000] (dir=1 time-reversed).
// ---------------------------------------------------------------------------
__global__ __launch_bounds__(256)
void gemm_proj(const float* __restrict__ A, int K,
               const float* __restrict__ W,
               const float* __restrict__ bi,
               const float* __restrict__ bh,
               float* __restrict__ xpT)
{
    __shared__ __align__(16) float As[32][68];    // [k][m]
    __shared__ __align__(16) float Bs[32][132];   // [k][n]

    const int tid = threadIdx.x;
    const int m0 = blockIdx.x * 64;
    const int n0 = blockIdx.y * 128;
    const int tx = tid & 15;     // m-quad
    const int ty = tid >> 4;     // n-octet

    float acc[8][4];
#pragma unroll
    for (int i = 0; i < 8; ++i)
#pragma unroll
        for (int jj = 0; jj < 4; ++jj) acc[i][jj] = 0.0f;

    const int ar = tid >> 3;
    const int ak = (tid & 7) * 4;
    const int wr = tid >> 1;
    const int wk = (tid & 1) * 16;

    for (int k0 = 0; k0 < K; k0 += 32) {
        float4 a0 = *(const float4*)(A + (size_t)(m0 + ar) * K + k0 + ak);
        float4 a1 = *(const float4*)(A + (size_t)(m0 + ar + 32) * K + k0 + ak);
        const float* wp = W + (size_t)(n0 + wr) * K + k0 + wk;
        float4 w0 = *(const float4*)(wp + 0);
        float4 w1 = *(const float4*)(wp + 4);
        float4 w2 = *(const float4*)(wp + 8);
        float4 w3 = *(const float4*)(wp + 12);

        __syncthreads();
        As[ak + 0][ar] = a0.x; As[ak + 1][ar] = a0.y;
        As[ak + 2][ar] = a0.z; As[ak + 3][ar] = a0.w;
        As[ak + 0][ar + 32] = a1.x; As[ak + 1][ar + 32] = a1.y;
        As[ak + 2][ar + 32] = a1.z; As[ak + 3][ar + 32] = a1.w;
        {
            float wv[16] = {w0.x, w0.y, w0.z, w0.w,
                            w1.x, w1.y, w1.z, w1.w,
                            w2.x, w2.y, w2.z, w2.w,
                            w3.x, w3.y, w3.z, w3.w};
#pragma unroll
            for (int q = 0; q < 16; ++q) Bs[wk + q][wr] = wv[q];
        }
        __syncthreads();

#pragma unroll
        for (int kk = 0; kk < 32; ++kk) {
            float4 av = *(const float4*)&As[kk][tx * 4];
            float4 b0 = *(const float4*)&Bs[kk][ty * 8];
            float4 b1 = *(const float4*)&Bs[kk][ty * 8 + 4];
            float bn[8] = {b0.x, b0.y, b0.z, b0.w, b1.x, b1.y, b1.z, b1.w};
#pragma unroll
            for (int ni = 0; ni < 8; ++ni) {
                acc[ni][0] = fmaf(av.x, bn[ni], acc[ni][0]);
                acc[ni][1] = fmaf(av.y, bn[ni], acc[ni][1]);
                acc[ni][2] = fmaf(av.z, bn[ni], acc[ni][2]);
                acc[ni][3] = fmaf(av.w, bn[ni], acc[ni][3]);
            }
        }
    }

    const int dir = n0 >> 7;
    const int mbase = m0 + tx * 4;
    const int bidx = mbase / 1000;
    const int ttq = mbase - bidx * 1000;
#pragma unroll
    for (int ni = 0; ni < 8; ++ni) {
        const int n = n0 + ty * 8 + ni;
        const float bias = bi[n] + bh[n];
        const float sc = (((n >> 5) & 3) == 2) ? (-2.0f * LOG2E) : (-LOG2E);
        float* row = xpT + ((size_t)((dir * 32 + bidx) * 128) + (n & 127)) * TB;
        if (dir == 0) {
            float4 o = {(acc[ni][0] + bias) * sc, (acc[ni][1] + bias) * sc,
                        (acc[ni][2] + bias) * sc, (acc[ni][3] + bias) * sc};
            *(float4*)(row + ttq) = o;
        } else {
            float4 o = {(acc[ni][3] + bias) * sc, (acc[ni][2] + bias) * sc,
                        (acc[ni][1] + bias) * sc, (acc[ni][0] + bias) * sc};
            *(float4*)(row + (TB - 4 - ttq)) = o;
        }
    }
}

// ---------------------------------------------------------------------------
// Recurrence: one wave per (dir,b). Lane l owns gate rows r0=(l&31)+(l>=32?64:0)
// and r1=r0+32 (i/f on lanes<32, g/o on lanes>=32, both halves redundant).
// h broadcast + matvec: matvec_rl (pipelined readlane/pk_fma asm).
// Gates arrive prescaled (-log2e, g-rows -2log2e): exp2 direct.
// ---------------------------------------------------------------------------
template<int MODE>
__global__ __launch_bounds__(64)
void lstm_rec(const float* __restrict__ xpT,  // [64][128][1000] prescaled
              const float* __restrict__ whh,  // [2][128][32]
              float* __restrict__ hout,       // [32][1000][64]
              float* __restrict__ hsum)       // [32][64]
{
    const int blk  = blockIdx.x;   // dir*32 + b
    const int dir  = blk >> 5;
    const int b    = blk & 31;
    const int lane = threadIdx.x & 63;
    const int j    = lane & 31;
    const int up   = lane >> 5;
    const int r0   = j + up * 64;
    const int r1   = r0 + 32;

    v2i det = __builtin_amdgcn_permlane32_swap(lane, lane, false, false);
    const bool pickx = (det[0] == (lane ^ 32));

    // recurrent weights, packed float2, prescaled: wa[i] = w[2i..2i+1]
    const float sA = up ? (-2.0f * LOG2E) : (-LOG2E);
    const float sB = -LOG2E;
    v2f wa[16], wb[16];
    {
        const float* wp0 = whh + (size_t)(dir * 128 + r0) * 32;
        const float* wp1 = whh + (size_t)(dir * 128 + r1) * 32;
#pragma unroll
        for (int q = 0; q < 8; ++q) {
            float4 v = *(const float4*)(wp0 + q * 4);
            wa[2 * q + 0][0] = v.x * sA; wa[2 * q + 0][1] = v.y * sA;
            wa[2 * q + 1][0] = v.z * sA; wa[2 * q + 1][1] = v.w * sA;
            float4 u = *(const float4*)(wp1 + q * 4);
            wb[2 * q + 0][0] = u.x * sB; wb[2 * q + 0][1] = u.y * sB;
            wb[2 * q + 1][0] = u.z * sB; wb[2 * q + 1][1] = u.w * sB;
        }
    }

    const float* pa = xpT + ((size_t)blk * 128 + r0) * TB;
    const float* pb = xpT + ((size_t)blk * 128 + r1) * TB;

    float4 A0 = *(const float4*)(pa + 0);
    float4 B0 = *(const float4*)(pb + 0);
    float4 A1 = *(const float4*)(pa + 4);
    float4 B1 = *(const float4*)(pb + 4);

    const float mA = up ?  2.0f : 1.0f;
    const float mB = up ? -1.0f : 0.0f;

    float c = 0.0f, h = 0.0f, hacc = 0.0f;
    float* hq = hout + ((size_t)b * TB + (dir ? TB - 1 : 0)) * 64 + dir * 32 + j;
    const int hstep = dir ? -64 : 64;

#define LSTM_STEP(GA, GB) do {                                                  \
        float g0, g1;                                                           \
        matvec_rl(__float_as_int(h), wa, wb, (GA), (GB), g0, g1);               \
        float s0 = __builtin_amdgcn_rcpf(1.0f + fexp2(g0));                     \
        float v0 = fmaf(mA, s0, mB);   /* lo: sig(i); hi: tanh(g) */            \
        float v1 = __builtin_amdgcn_rcpf(1.0f + fexp2(g1)); /* sig(f)/sig(o) */ \
        float o0 = lane_xor32(v0, pickx);                                       \
        float o1 = lane_xor32(v1, pickx);                                       \
        float P  = v0 * o0;            /* == si*tg in BOTH halves */            \
        float sf = up ? o1 : v1;                                                \
        float so = up ? v1 : o1;                                                \
        c = fmaf(sf, c, P);                                                     \
        float tc = fmaf(2.0f, __builtin_amdgcn_rcpf(1.0f + fexp2(c * (-2.0f * LOG2E))), -1.0f); \
        h = so * tc;                                                            \
        if (MODE == 0) *hq = h; else hacc += h;                                 \
        hq += hstep;                                                            \
    } while (0)

    for (int it = 0; it < 125; ++it) {
        const int base = it * 8;
        const int offn0 = min(base + 8,  TB - 4);   // clamped, unconditional
        const int offn1 = min(base + 12, TB - 4);
        float4 NA0 = *(const float4*)(pa + offn0);
        float4 NB0 = *(const float4*)(pb + offn0);
        float4 NA1 = *(const float4*)(pa + offn1);
        float4 NB1 = *(const float4*)(pb + offn1);

        LSTM_STEP(A0.x, B0.x);
        LSTM_STEP(A0.y, B0.y);
        LSTM_STEP(A0.z, B0.z);
        LSTM_STEP(A0.w, B0.w);
        LSTM_STEP(A1.x, B1.x);
        LSTM_STEP(A1.y, B1.y);
        LSTM_STEP(A1.z, B1.z);
        LSTM_STEP(A1.w, B1.w);

        A0 = NA0; B0 = NB0; A1 = NA1; B1 = NB1;
    }
#undef LSTM_STEP

    if (MODE == 1) hsum[b * 64 + dir * 32 + j] = hacc;
}

// ---------------------------------------------------------------------------
__global__ __launch_bounds__(64)
void final_fc(const float* __restrict__ hsum,
              const float* __restrict__ fcw,
              const float* __restrict__ fcb,
              float* __restrict__ out)
{
    int b = blockIdx.x;
    int l = threadIdx.x;
    float v = hsum[b * 64 + l] * (1.0f / (float)TB) * fcw[l];
#pragma unroll
    for (int off = 32; off > 0; off >>= 1)
        v += __shfl_down(v, off, 64);
    if (l == 0) out[b] = v + fcb[0];
}

// ---------------------------------------------------------------------------
extern "C" void kernel_launch(void* const* d_in, const int* in_sizes, int n_in,
                              void* d_out, int out_size, void* d_ws, size_t ws_size,
                              hipStream_t stream)
{
    const float* x    = (const float*)d_in[0];
    const float* wih0 = (const float*)d_in[1];
    const float* whh0 = (const float*)d_in[2];
    const float* bih0 = (const float*)d_in[3];
    const float* bhh0 = (const float*)d_in[4];
    const float* wih  = (const float*)d_in[5];
    const float* whh  = (const float*)d_in[6];
    const float* bih  = (const float*)d_in[7];
    const float* bhh  = (const float*)d_in[8];
    const float* fcw  = (const float*)d_in[9];
    const float* fcb  = (const float*)d_in[10];
    float* out = (float*)d_out;

    float* ws = (float*)d_ws;
    float* xp = ws;                         // 64*128*1000 floats
    float* hb = ws + 8192000;               // 32*1000*64 floats
    float* hs = ws + 8192000 + 2048000;     // 32*64

    dim3 gb(500, 2);

    gemm_proj<<<gb, 256, 0, stream>>>(x, 1024, wih0, bih0, bhh0, xp);
    lstm_rec<0><<<64, 64, 0, stream>>>(xp, whh0, hb, hs);

    for (int l = 1; l < 4; ++l) {
        const float* wl  = wih + (size_t)(l - 1) * 2 * 128 * 64;
        const float* whl = whh + (size_t)(l - 1) * 2 * 128 * 32;
        const float* b1  = bih + (size_t)(l - 1) * 256;
        const float* b2  = bhh + (size_t)(l - 1) * 256;
        gemm_proj<<<gb, 256, 0, stream>>>(hb, 64, wl, b1, b2, xp);
        if (l == 3) lstm_rec<1><<<64, 64, 0, stream>>>(xp, whl, hb, hs);
        else        lstm_rec<0><<<64, 64, 0, stream>>>(xp, whl, hb, hs);
    }

    final_fc<<<32, 64, 0, stream>>>(hs, fcw, fcb, out);
}

// Round 10
// 1033.067 us; speedup vs baseline: 1.2366x; 1.2366x over previous
//
#include <hip/hip_runtime.h>

// Wav2Vec BLSTM: 4-layer bi-LSTM (B=32, T=1000, H=32, G=128) + mean-pool + fc.
//
// Round 10 (r8/r9 + compile fix): staged lgkmcnt waits are plain no-operand
// volatile asm + sched_barrier(0) (rule #18); no tied 128-bit operands.
// LDS h-broadcast: 1 ds_write_b32 + 8 ds_read_b128 (volatile asm, in-order
// DS pipe); pk_fma group q runs after s_waitcnt lgkmcnt(7-q) so fma issue
// overlaps the read stream. h-store via asm global_store (lgkmcnt DS-only).
// Kept (verified bit-exact): -log2e / -2log2e prescale in weights + GEMM
// epilogue (exp2 direct), permlane32_swap exchange, P=v0*o0 select-free
// tail, transposed/time-reversed xpT streams, clamped unconditional
// prefetch, branch-free h store.

#define TB 1000
#define LOG2E 1.44269504088896340736f

typedef int   v2i __attribute__((ext_vector_type(2)));
typedef float v2f __attribute__((ext_vector_type(2)));

__device__ __forceinline__ float fexp2(float x) {
#if __has_builtin(__builtin_amdgcn_exp2f)
    return __builtin_amdgcn_exp2f(x);
#else
    return exp2f(x);
#endif
}

// returns v[lane ^ 32]; pickx precomputed per-lane (convention-independent)
__device__ __forceinline__ float lane_xor32(float v, bool pickx) {
    v2i r = __builtin_amdgcn_permlane32_swap(__float_as_int(v), __float_as_int(v),
                                             false, false);
    return __int_as_float(pickx ? r[0] : r[1]);
}

// ---------------------------------------------------------------------------
// GEMM: A[32000][K] x W[256][K]^T + (bi+bh), then row-dependent prescale by
// -log2e (g-rows: -2log2e) -> xpT[2*32][128][1000] (dir=1 time-reversed).
// ---------------------------------------------------------------------------
__global__ __launch_bounds__(256)
void gemm_proj(const float* __restrict__ A, int K,
               const float* __restrict__ W,
               const float* __restrict__ bi,
               const float* __restrict__ bh,
               float* __restrict__ xpT)
{
    __shared__ __align__(16) float As[32][68];    // [k][m]
    __shared__ __align__(16) float Bs[32][132];   // [k][n]

    const int tid = threadIdx.x;
    const int m0 = blockIdx.x * 64;
    const int n0 = blockIdx.y * 128;
    const int tx = tid & 15;     // m-quad
    const int ty = tid >> 4;     // n-octet

    float acc[8][4];
#pragma unroll
    for (int i = 0; i < 8; ++i)
#pragma unroll
        for (int jj = 0; jj < 4; ++jj) acc[i][jj] = 0.0f;

    const int ar = tid >> 3;
    const int ak = (tid & 7) * 4;
    const int wr = tid >> 1;
    const int wk = (tid & 1) * 16;

    for (int k0 = 0; k0 < K; k0 += 32) {
        float4 a0 = *(const float4*)(A + (size_t)(m0 + ar) * K + k0 + ak);
        float4 a1 = *(const float4*)(A + (size_t)(m0 + ar + 32) * K + k0 + ak);
        const float* wp = W + (size_t)(n0 + wr) * K + k0 + wk;
        float4 w0 = *(const float4*)(wp + 0);
        float4 w1 = *(const float4*)(wp + 4);
        float4 w2 = *(const float4*)(wp + 8);
        float4 w3 = *(const float4*)(wp + 12);

        __syncthreads();
        As[ak + 0][ar] = a0.x; As[ak + 1][ar] = a0.y;
        As[ak + 2][ar] = a0.z; As[ak + 3][ar] = a0.w;
        As[ak + 0][ar + 32] = a1.x; As[ak + 1][ar + 32] = a1.y;
        As[ak + 2][ar + 32] = a1.z; As[ak + 3][ar + 32] = a1.w;
        {
            float wv[16] = {w0.x, w0.y, w0.z, w0.w,
                            w1.x, w1.y, w1.z, w1.w,
                            w2.x, w2.y, w2.z, w2.w,
                            w3.x, w3.y, w3.z, w3.w};
#pragma unroll
            for (int q = 0; q < 16; ++q) Bs[wk + q][wr] = wv[q];
        }
        __syncthreads();

#pragma unroll
        for (int kk = 0; kk < 32; ++kk) {
            float4 av = *(const float4*)&As[kk][tx * 4];
            float4 b0 = *(const float4*)&Bs[kk][ty * 8];
            float4 b1 = *(const float4*)&Bs[kk][ty * 8 + 4];
            float bn[8] = {b0.x, b0.y, b0.z, b0.w, b1.x, b1.y, b1.z, b1.w};
#pragma unroll
            for (int ni = 0; ni < 8; ++ni) {
                acc[ni][0] = fmaf(av.x, bn[ni], acc[ni][0]);
                acc[ni][1] = fmaf(av.y, bn[ni], acc[ni][1]);
                acc[ni][2] = fmaf(av.z, bn[ni], acc[ni][2]);
                acc[ni][3] = fmaf(av.w, bn[ni], acc[ni][3]);
            }
        }
    }

    const int dir = n0 >> 7;
    const int mbase = m0 + tx * 4;
    const int bidx = mbase / 1000;
    const int ttq = mbase - bidx * 1000;
#pragma unroll
    for (int ni = 0; ni < 8; ++ni) {
        const int n = n0 + ty * 8 + ni;
        const float bias = bi[n] + bh[n];
        const float sc = (((n >> 5) & 3) == 2) ? (-2.0f * LOG2E) : (-LOG2E);
        float* row = xpT + ((size_t)((dir * 32 + bidx) * 128) + (n & 127)) * TB;
        if (dir == 0) {
            float4 o = {(acc[ni][0] + bias) * sc, (acc[ni][1] + bias) * sc,
                        (acc[ni][2] + bias) * sc, (acc[ni][3] + bias) * sc};
            *(float4*)(row + ttq) = o;
        } else {
            float4 o = {(acc[ni][3] + bias) * sc, (acc[ni][2] + bias) * sc,
                        (acc[ni][1] + bias) * sc, (acc[ni][0] + bias) * sc};
            *(float4*)(row + (TB - 4 - ttq)) = o;
        }
    }
}

// ---------------------------------------------------------------------------
// Recurrence: one wave per (dir,b). Lane l owns gate rows r0=(l&31)+(l>=32?64:0)
// and r1=r0+32 (i/f on lanes<32, g/o on lanes>=32, both halves redundant).
// h broadcast: ds_write_b32 + 8x ds_read_b128 with STAGED lgkmcnt waits.
// Gates arrive prescaled (-log2e, g-rows -2log2e): exp2 direct.
// ---------------------------------------------------------------------------
template<int MODE>
__global__ __launch_bounds__(64)
void lstm_rec(const float* __restrict__ xpT,  // [64][128][1000] prescaled
              const float* __restrict__ whh,  // [2][128][32]
              float* __restrict__ hout,       // [32][1000][64]
              float* __restrict__ hsum)       // [32][64]
{
    __shared__ __align__(16) float hsh[32];

    const int blk  = blockIdx.x;   // dir*32 + b
    const int dir  = blk >> 5;
    const int b    = blk & 31;
    const int lane = threadIdx.x & 63;
    const int j    = lane & 31;
    const int up   = lane >> 5;
    const int r0   = j + up * 64;
    const int r1   = r0 + 32;

    v2i det = __builtin_amdgcn_permlane32_swap(lane, lane, false, false);
    const bool pickx = (det[0] == (lane ^ 32));

    // recurrent weights, packed float2, prescaled: wa[i] = w[2i..2i+1]
    const float sA = up ? (-2.0f * LOG2E) : (-LOG2E);
    const float sB = -LOG2E;
    v2f wa[16], wb[16];
    {
        const float* wp0 = whh + (size_t)(dir * 128 + r0) * 32;
        const float* wp1 = whh + (size_t)(dir * 128 + r1) * 32;
#pragma unroll
        for (int q = 0; q < 8; ++q) {
            float4 v = *(const float4*)(wp0 + q * 4);
            wa[2 * q + 0][0] = v.x * sA; wa[2 * q + 0][1] = v.y * sA;
            wa[2 * q + 1][0] = v.z * sA; wa[2 * q + 1][1] = v.w * sA;
            float4 u = *(const float4*)(wp1 + q * 4);
            wb[2 * q + 0][0] = u.x * sB; wb[2 * q + 0][1] = u.y * sB;
            wb[2 * q + 1][0] = u.z * sB; wb[2 * q + 1][1] = u.w * sB;
        }
    }

    const float* pa = xpT + ((size_t)blk * 128 + r0) * TB;
    const float* pb = xpT + ((size_t)blk * 128 + r1) * TB;

    float4 A0 = *(const float4*)(pa + 0);
    float4 B0 = *(const float4*)(pb + 0);
    float4 A1 = *(const float4*)(pa + 4);
    float4 B1 = *(const float4*)(pb + 4);

    const float mA = up ?  2.0f : 1.0f;
    const float mB = up ? -1.0f : 0.0f;

    float c = 0.0f, h = 0.0f, hacc = 0.0f;
    float* hq = hout + ((size_t)b * TB + (dir ? TB - 1 : 0)) * 64 + dir * 32 + j;
    const int hstep = dir ? -64 : 64;

    // LDS byte offsets (addrspace(3) offset via low-32 truncation)
    const unsigned lds_z  = (unsigned)(size_t)&hsh[0];
    const unsigned lds_wa = lds_z + 4u * (unsigned)j;

    float4 hv0, hv1, hv2, hv3, hv4v, hv5, hv6, hv7;

#define DS_WRITE_H() \
    asm volatile("ds_write_b32 %0, %1" :: "v"(lds_wa), "v"(h))

#define DS_ISSUE_READS() do {                                                   \
    asm volatile("ds_read_b128 %0, %1 offset:0"   : "=v"(hv0)  : "v"(lds_z));   \
    asm volatile("ds_read_b128 %0, %1 offset:16"  : "=v"(hv1)  : "v"(lds_z));   \
    asm volatile("ds_read_b128 %0, %1 offset:32"  : "=v"(hv2)  : "v"(lds_z));   \
    asm volatile("ds_read_b128 %0, %1 offset:48"  : "=v"(hv3)  : "v"(lds_z));   \
    asm volatile("ds_read_b128 %0, %1 offset:64"  : "=v"(hv4v) : "v"(lds_z));   \
    asm volatile("ds_read_b128 %0, %1 offset:80"  : "=v"(hv5)  : "v"(lds_z));   \
    asm volatile("ds_read_b128 %0, %1 offset:96"  : "=v"(hv6)  : "v"(lds_z));   \
    asm volatile("ds_read_b128 %0, %1 offset:112" : "=v"(hv7)  : "v"(lds_z));   \
    } while (0)

// staged wait: no-operand volatile asm + sched_barrier(0) fence (rule #18).
// Volatile asm blocks keep mutual order; sched_barrier stops the consuming
// fmas from hoisting above the wait.
#define MVG(HV, CNT, I0, I1, Q)                                                 \
    asm volatile("s_waitcnt lgkmcnt(" #CNT ")");                                \
    __builtin_amdgcn_sched_barrier(0);                                          \
    {                                                                           \
        v2f h0_ = {HV.x, HV.y};                                                 \
        v2f h1_ = {HV.z, HV.w};                                                 \
        qa[I0] = __builtin_elementwise_fma(h0_, wa[2*Q],   qa[I0]);             \
        qb[I0] = __builtin_elementwise_fma(h0_, wb[2*Q],   qb[I0]);             \
        qa[I1] = __builtin_elementwise_fma(h1_, wa[2*Q+1], qa[I1]);             \
        qb[I1] = __builtin_elementwise_fma(h1_, wb[2*Q+1], qb[I1]);             \
    }

    // prologue: publish h(0)=0 and issue the first read batch
    DS_WRITE_H();
    DS_ISSUE_READS();

#define LSTM_STEP(GA, GB) do {                                                  \
        v2f qa[4], qb[4];                                                       \
        qa[0] = v2f{(GA), 0.0f}; qa[1] = v2f{0.f, 0.f};                         \
        qa[2] = v2f{0.f, 0.f};   qa[3] = v2f{0.f, 0.f};                         \
        qb[0] = v2f{(GB), 0.0f}; qb[1] = v2f{0.f, 0.f};                         \
        qb[2] = v2f{0.f, 0.f};   qb[3] = v2f{0.f, 0.f};                         \
        MVG(hv0,  7, 0, 1, 0)                                                   \
        MVG(hv1,  6, 2, 3, 1)                                                   \
        MVG(hv2,  5, 0, 1, 2)                                                   \
        MVG(hv3,  4, 2, 3, 3)                                                   \
        MVG(hv4v, 3, 0, 1, 4)                                                   \
        MVG(hv5,  2, 2, 3, 5)                                                   \
        MVG(hv6,  1, 0, 1, 6)                                                   \
        MVG(hv7,  0, 2, 3, 7)                                                   \
        v2f sa = (qa[0] + qa[2]) + (qa[1] + qa[3]);                             \
        v2f sb = (qb[0] + qb[2]) + (qb[1] + qb[3]);                             \
        float g0 = sa[0] + sa[1];                                               \
        float g1 = sb[0] + sb[1];                                               \
        float s0 = __builtin_amdgcn_rcpf(1.0f + fexp2(g0));                     \
        float v0 = fmaf(mA, s0, mB);   /* lo: sig(i); hi: tanh(g) */            \
        float v1 = __builtin_amdgcn_rcpf(1.0f + fexp2(g1)); /* sig(f)/sig(o) */ \
        float o0 = lane_xor32(v0, pickx);                                       \
        float o1 = lane_xor32(v1, pickx);                                       \
        float P  = v0 * o0;            /* == si*tg in BOTH halves */            \
        float sf = up ? o1 : v1;                                                \
        float so = up ? v1 : o1;                                                \
        c = fmaf(sf, c, P);                                                     \
        float tc = fmaf(2.0f, __builtin_amdgcn_rcpf(1.0f + fexp2(c * (-2.0f * LOG2E))), -1.0f); \
        h = so * tc;                                                            \
        DS_WRITE_H();                                                           \
        DS_ISSUE_READS();                                                       \
        if (MODE == 0) {                                                        \
            asm volatile("global_store_dword %0, %1, off" :: "v"(hq), "v"(h));  \
        } else {                                                                \
            hacc += h;                                                          \
        }                                                                       \
        hq += hstep;                                                            \
    } while (0)

    for (int it = 0; it < 125; ++it) {
        const int base = it * 8;
        const int offn0 = min(base + 8,  TB - 4);   // clamped, unconditional
        const int offn1 = min(base + 12, TB - 4);
        float4 NA0 = *(const float4*)(pa + offn0);
        float4 NB0 = *(const float4*)(pb + offn0);
        float4 NA1 = *(const float4*)(pa + offn1);
        float4 NB1 = *(const float4*)(pb + offn1);

        LSTM_STEP(A0.x, B0.x);
        LSTM_STEP(A0.y, B0.y);
        LSTM_STEP(A0.z, B0.z);
        LSTM_STEP(A0.w, B0.w);
        LSTM_STEP(A1.x, B1.x);
        LSTM_STEP(A1.y, B1.y);
        LSTM_STEP(A1.z, B1.z);
        LSTM_STEP(A1.w, B1.w);

        A0 = NA0; B0 = NB0; A1 = NA1; B1 = NB1;
    }
#undef LSTM_STEP
#undef MVG
#undef DS_ISSUE_READS
#undef DS_WRITE_H

    // drain the dangling read batch before exit
    asm volatile("s_waitcnt lgkmcnt(0)" ::: "memory");

    if (MODE == 1) hsum[b * 64 + dir * 32 + j] = hacc;
}

// ---------------------------------------------------------------------------
__global__ __launch_bounds__(64)
void final_fc(const float* __restrict__ hsum,
              const float* __restrict__ fcw,
              const float* __restrict__ fcb,
              float* __restrict__ out)
{
    int b = blockIdx.x;
    int l = threadIdx.x;
    float v = hsum[b * 64 + l] * (1.0f / (float)TB) * fcw[l];
#pragma unroll
    for (int off = 32; off > 0; off >>= 1)
        v += __shfl_down(v, off, 64);
    if (l == 0) out[b] = v + fcb[0];
}

// ---------------------------------------------------------------------------
extern "C" void kernel_launch(void* const* d_in, const int* in_sizes, int n_in,
                              void* d_out, int out_size, void* d_ws, size_t ws_size,
                              hipStream_t stream)
{
    const float* x    = (const float*)d_in[0];
    const float* wih0 = (const float*)d_in[1];
    const float* whh0 = (const float*)d_in[2];
    const float* bih0 = (const float*)d_in[3];
    const float* bhh0 = (const float*)d_in[4];
    const float* wih  = (const float*)d_in[5];
    const float* whh  = (const float*)d_in[6];
    const float* bih  = (const float*)d_in[7];
    const float* bhh  = (const float*)d_in[8];
    const float* fcw  = (const float*)d_in[9];
    const float* fcb  = (const float*)d_in[10];
    float* out = (float*)d_out;

    float* ws = (float*)d_ws;
    float* xp = ws;                         // 64*128*1000 floats
    float* hb = ws + 8192000;               // 32*1000*64 floats
    float* hs = ws + 8192000 + 2048000;     // 32*64

    dim3 gb(500, 2);

    gemm_proj<<<gb, 256, 0, stream>>>(x, 1024, wih0, bih0, bhh0, xp);
    lstm_rec<0><<<64, 64, 0, stream>>>(xp, whh0, hb, hs);

    for (int l = 1; l < 4; ++l) {
        const float* wl  = wih + (size_t)(l - 1) * 2 * 128 * 64;
        const float* whl = whh + (size_t)(l - 1) * 2 * 128 * 32;
        const float* b1  = bih + (size_t)(l - 1) * 256;
        const float* b2  = bhh + (size_t)(l - 1) * 256;
        gemm_proj<<<gb, 256, 0, stream>>>(hb, 64, wl, b1, b2, xp);
        if (l == 3) lstm_rec<1><<<64, 64, 0, stream>>>(xp, whl, hb, hs);
        else        lstm_rec<0><<<64, 64, 0, stream>>>(xp, whl, hb, hs);
    }

    final_fc<<<32, 64, 0, stream>>>(hs, fcw, fcb, out);
}